// Round 9
// baseline (81.700 us; speedup 1.0000x reference)
//
#include <hip/hip_runtime.h>
#include <hip/hip_bf16.h>
#include <math.h>

typedef unsigned short u16;
typedef unsigned int   u32;
typedef __attribute__((ext_vector_type(8))) short short8;
typedef __attribute__((ext_vector_type(4))) float f32x4;

// Problem constants
#define B_  4
#define C_  64
#define H_  128
#define W_  128
#define O_  64
#define HW_ (H_ * W_)

__device__ __forceinline__ u16 f2bf(float f) {
    __hip_bfloat16 h = __float2bfloat16(f);
    u16 u; __builtin_memcpy(&u, &h, 2); return u;
}
__device__ __forceinline__ float bf2f(u16 u) {
    return __uint_as_float((u32)u << 16);
}
// pack two f32 -> [hi|lo] bf16 pair, hardware RNE (no builtin on gfx950)
__device__ __forceinline__ u32 cvt_pk_bf16(float lo, float hi) {
    u32 r; asm("v_cvt_pk_bf16_f32 %0, %1, %2" : "=v"(r) : "v"(lo), "v"(hi));
    return r;
}
__device__ __forceinline__ float bflo(u32 v) { return __uint_as_float(v << 16); }
__device__ __forceinline__ float bfhi(u32 v) { return __uint_as_float(v & 0xffff0000u); }

// -------------------------------------------------------------------------
// repack: Wb  (4 otile,18 ks,64 lane,8 j) bf16  from weight (O,C,3,3)
//         OWb (2 otile,18 ks,64 lane,8 j) bf16  from ow|mw|0
// K index convention: kidx = tap*64 + c  (tap-major, channel minor)
// A-frag (16x16x32): lane l holds A[o = l&15][k = ks*32 + (l>>4)*8 + j]
// -------------------------------------------------------------------------
__global__ __launch_bounds__(256) void repack(
    const float* __restrict__ weight,
    const float* __restrict__ ow, const float* __restrict__ mw,
    u16* __restrict__ Wb, u16* __restrict__ OWb)
{
    int t = blockIdx.x * 256 + threadIdx.x;      // 216 blocks = 55296 threads
    if (t < 36864) {                             // Wb
        int e = t;
        int j = e & 7, ln = (e >> 3) & 63;
        int ks = (e >> 9) % 18, ot = e / 9216;
        int o = ot * 16 + (ln & 15);
        int kidx = ks * 32 + ((ln >> 4) << 3) + j;
        int k = kidx >> 6, c = kidx & 63;
        Wb[e] = f2bf(weight[((size_t)(o * 64 + c)) * 9 + k]);
    } else {                                     // OWb
        int e = t - 36864;
        int j = e & 7, ln = (e >> 3) & 63;
        int ks = (e >> 9) % 18, ot = e / 9216;
        int o = ot * 16 + (ln & 15);
        int kidx = ks * 32 + ((ln >> 4) << 3) + j;
        int k = kidx >> 6, c = kidx & 63;
        float v = 0.0f;
        if (o < 18)      v = ow[((size_t)(o * 64 + c)) * 9 + k];
        else if (o < 27) v = mw[((size_t)((o - 18) * 64 + c)) * 9 + k];
        OWb[e] = f2bf(v);
    }
}

// -------------------------------------------------------------------------
// prep_t: transpose all 4 batches of x (B,C,H,W) f32 -> xt (B,H,W,C) bf16
// -------------------------------------------------------------------------
__global__ __launch_bounds__(256) void prep_t(
    const float* __restrict__ x, u16* __restrict__ xt)
{
    __shared__ float tile[64][65];
    int i = blockIdx.x, t = threadIdx.x;        // 1024 blocks
    int lb = i >> 8;                            // 0..3
    int pix0 = (i & 255) << 6;
    const float* xb = x + ((size_t)lb << 20);   // lb * C*HW
#pragma unroll
    for (int it = 0; it < 16; ++it) {
        int e = it * 256 + t;
        int c = e >> 6, pl = e & 63;
        tile[c][pl] = xb[((size_t)c << 14) + pix0 + pl];
    }
    __syncthreads();
    u16* xo = xt + ((((size_t)lb << 14) + pix0) << 6);
#pragma unroll
    for (int it = 0; it < 16; ++it) {
        int e = it * 256 + t;
        int c = e & 63, pl = e >> 6;
        xo[((size_t)pl << 6) + c] = f2bf(tile[c][pl]);
    }
}

// -------------------------------------------------------------------------
// fused_dcn: CHANNEL-SPLIT wave pairs. Block = 256 = 4 waves = 2 pixel
// groups x 2 channel-halves. Each pixel group (16 pixels, one row segment)
// is owned by a wave PAIR (k2h = 0,1):
//   K1  : otile k2h of the offset/mask conv (18 MFMAs), B-frags direct
//         from global xt (regular im2col, cndmask zero-pad) -> param LDS
//   st1 : bilinear corner byte-offsets (int4) + bf16 weights, 144 pairs
//         split over the pair's 128 lanes
//   K2  : per tap: wave k2h gathers its 32-channel half (4 x dwordx4 per
//         lane), interpolates in f32, cvt_pk -> B-frag in registers,
//         4 o-tile MFMAs with ks = tap*2+k2h (partial-K accumulate).
//         Tap loop unrolled x3 for memory-level parallelism (12 gathers
//         in flight per wave) — needs the VGPR headroom from bounds(,6).
//   red : k2h=1 writes partial acc (4 KB LDS, overlaid on dead pwp),
//         k2h=0 adds and stores all 64 output channels.
// 8192 waves total; LDS 15 KB; launch_bounds(256,6) -> VGPR<=85, no spill.
// -------------------------------------------------------------------------
__global__ __launch_bounds__(256, 6) void fused_dcn(
    const u16* __restrict__ xt,
    const u16* __restrict__ Wb, const u16* __restrict__ OWb,
    const float* __restrict__ ob, const float* __restrict__ mb,
    float* __restrict__ out)
{
    __shared__ float param[2][27][16];              //  3456 B
    __shared__ __align__(16) char scratch[2][5760]; // 11520 B: pwp|pww, later red

    const int t = threadIdx.x;
    const int lane = t & 63;
    const int wv = t >> 6;          // 0..3
    const int pg = wv >> 1;         // pixel group 0..1
    const int k2h = wv & 1;         // channel half / K1 o-tile
    const int mypix = lane & 15;
    const int hi = lane >> 4;       // channel octet within half

    int bid0 = blockIdx.x;          // 2048 blocks
    const int bid = (bid0 & 7) * 256 + (bid0 >> 3);   // XCD swizzle (bijective)
    const int task = (bid << 1) + pg;  // 0..4095 pixel-group task
    const int lb = task >> 10;      // batch
    const int pix0 = (task & 1023) << 4;
    const int h  = pix0 >> 7;       // 16 pixels share one row
    const int w0 = pix0 & 127;

    const u16* xtb = xt + ((size_t)lb << 20);
    int4*    pwp = (int4*)(scratch[pg]);            // 144 * 16 = 4608 B
    ushort4* pww = (ushort4*)(scratch[pg] + 4608);  // 144 *  8 = 1152 B

    // ---- K1: offset/mask conv, o-tile = k2h, direct global im2col ----
    f32x4 k1 = {0.f, 0.f, 0.f, 0.f};
#pragma unroll
    for (int ks = 0; ks < 18; ++ks) {
        const int tap = ks >> 1;
        const int ky = tap / 3, kx = tap % 3;
        int y  = h - 1 + ky;
        int xx = w0 + mypix - 1 + kx;
        bool valid = ((unsigned)y < (unsigned)H_) && ((unsigned)xx < (unsigned)W_);
        int idx = ((y & 127) << 7) + (xx & 127);    // wrapped -> safe address
        uint4 raw = *(const uint4*)(xtb + ((size_t)idx << 6) + ((ks & 1) << 5) + (hi << 3));
        raw.x = valid ? raw.x : 0u;
        raw.y = valid ? raw.y : 0u;
        raw.z = valid ? raw.z : 0u;
        raw.w = valid ? raw.w : 0u;
        short8 bfr;
        __builtin_memcpy(&bfr, &raw, 16);
        short8 wa = ((const short8*)OWb)[(k2h * 18 + ks) * 64 + lane];
        k1 = __builtin_amdgcn_mfma_f32_16x16x32_bf16(wa, bfr, k1, 0, 0, 0);
    }
#pragma unroll
    for (int r = 0; r < 4; ++r) {
        int oc = (k2h << 4) + (hi << 2) + r;
        if (oc < 18) {
            param[pg][oc][mypix] = k1[r] + ob[oc];
        } else if (oc < 27) {
            float s = k1[r] + mb[oc - 18];
            param[pg][oc][mypix] = 2.0f / (1.0f + __expf(-s));
        }
    }
    __syncthreads();

    // ---- step 1: bilinear corner offsets + weights (pair's 128 lanes) ----
    {
        int t128 = (k2h << 6) + lane;
#pragma unroll
        for (int it = 0; it < 2; ++it) {
            int p = (it << 7) + t128;
            if (p < 144) {
                int tap = p >> 4, pixl = p & 15;
                int ky = tap / 3, kx = tap % 3;
                float dy = param[pg][2 * tap][pixl];
                float dx = param[pg][2 * tap + 1][pixl];
                float m  = param[pg][18 + tap][pixl];
                float py = (float)(h - 1 + ky) + dy;
                float px = (float)(w0 + pixl - 1 + kx) + dx;
                float y0f = floorf(py), x0f = floorf(px);
                float fy = py - y0f, fx = px - x0f;
                int y0 = (int)y0f, x0 = (int)x0f;
                int y1 = y0 + 1, x1 = x0 + 1;
                bool vy0 = (unsigned)y0 < (unsigned)H_;
                bool vy1 = (unsigned)y1 < (unsigned)H_;
                bool vx0 = (unsigned)x0 < (unsigned)W_;
                bool vx1 = (unsigned)x1 < (unsigned)W_;
                float w00 = (1.f - fy) * (1.f - fx) * m; if (!(vy0 && vx0)) w00 = 0.f;
                float w01 = (1.f - fy) * fx          * m; if (!(vy0 && vx1)) w01 = 0.f;
                float w10 = fy * (1.f - fx)          * m; if (!(vy1 && vx0)) w10 = 0.f;
                float w11 = fy * fx                   * m; if (!(vy1 && vx1)) w11 = 0.f;
                int y0c = min(max(y0, 0), H_ - 1);
                int y1c = min(max(y1, 0), H_ - 1);
                int x0c = min(max(x0, 0), W_ - 1);
                int x1c = min(max(x1, 0), W_ - 1);
                // byte offsets into xt batch slab: pos (elem) * 64ch * 2B = pos<<7
                pwp[p] = make_int4(((y0c << 7) + x0c) << 7, ((y0c << 7) + x1c) << 7,
                                   ((y1c << 7) + x0c) << 7, ((y1c << 7) + x1c) << 7);
                pww[p] = make_ushort4(f2bf(w00), f2bf(w01), f2bf(w10), f2bf(w11));
            }
        }
    }
    __syncthreads();

    // ---- K2: gather own channel half + in-register B-frag + 4 MFMAs/tap ----
    f32x4 acc0 = {0.f,0.f,0.f,0.f}, acc1 = {0.f,0.f,0.f,0.f};
    f32x4 acc2 = {0.f,0.f,0.f,0.f}, acc3 = {0.f,0.f,0.f,0.f};
    const char* xb8 = (const char*)xtb;
    const int co = (hi << 4) + (k2h << 6);     // byte offset of my channel octet
#pragma unroll 3
    for (int tap = 0; tap < 9; ++tap) {
        int4    ofs = pwp[(tap << 4) + mypix];
        ushort4 wq  = pww[(tap << 4) + mypix];
        float wtx = bf2f(wq.x), wty = bf2f(wq.y);
        float wtz = bf2f(wq.z), wtw = bf2f(wq.w);
        uint4 r00 = *(const uint4*)(xb8 + ofs.x + co);
        uint4 r01 = *(const uint4*)(xb8 + ofs.y + co);
        uint4 r10 = *(const uint4*)(xb8 + ofs.z + co);
        uint4 r11 = *(const uint4*)(xb8 + ofs.w + co);
        const u32* q00 = (const u32*)&r00;
        const u32* q01 = (const u32*)&r01;
        const u32* q10 = (const u32*)&r10;
        const u32* q11 = (const u32*)&r11;
        u32 bw[4];
#pragma unroll
        for (int q = 0; q < 4; ++q) {
            float slo = bflo(q00[q]) * wtx;
            slo = fmaf(bflo(q01[q]), wty, slo);
            slo = fmaf(bflo(q10[q]), wtz, slo);
            slo = fmaf(bflo(q11[q]), wtw, slo);
            float shi = bfhi(q00[q]) * wtx;
            shi = fmaf(bfhi(q01[q]), wty, shi);
            shi = fmaf(bfhi(q10[q]), wtz, shi);
            shi = fmaf(bfhi(q11[q]), wtw, shi);
            bw[q] = cvt_pk_bf16(slo, shi);
        }
        short8 bfr;
        __builtin_memcpy(&bfr, bw, 16);
        int ks = (tap << 1) + k2h;
        short8 a0 = ((const short8*)Wb)[(0 * 18 + ks) * 64 + lane];
        short8 a1 = ((const short8*)Wb)[(1 * 18 + ks) * 64 + lane];
        short8 a2 = ((const short8*)Wb)[(2 * 18 + ks) * 64 + lane];
        short8 a3 = ((const short8*)Wb)[(3 * 18 + ks) * 64 + lane];
        acc0 = __builtin_amdgcn_mfma_f32_16x16x32_bf16(a0, bfr, acc0, 0, 0, 0);
        acc1 = __builtin_amdgcn_mfma_f32_16x16x32_bf16(a1, bfr, acc1, 0, 0, 0);
        acc2 = __builtin_amdgcn_mfma_f32_16x16x32_bf16(a2, bfr, acc2, 0, 0, 0);
        acc3 = __builtin_amdgcn_mfma_f32_16x16x32_bf16(a3, bfr, acc3, 0, 0, 0);
    }
    __syncthreads();                    // all K2 reads of pwp/pww done

    // ---- reduce across the wave pair (red overlays dead pwp/pww) ----
    float* red = (float*)scratch[pg];   // 16 * 64 * 4 = 4096 B
    if (k2h) {
#pragma unroll
        for (int r = 0; r < 4; ++r) {
            red[( 0 + r) * 64 + lane] = acc0[r];
            red[( 4 + r) * 64 + lane] = acc1[r];
            red[( 8 + r) * 64 + lane] = acc2[r];
            red[(12 + r) * 64 + lane] = acc3[r];
        }
    }
    __syncthreads();
    if (!k2h) {
        float* op = out + ((size_t)lb << 20) + pix0 + mypix;
#pragma unroll
        for (int r = 0; r < 4; ++r) {
            op[(size_t)( 0 + (hi << 2) + r) << 14] = acc0[r] + red[( 0 + r) * 64 + lane];
            op[(size_t)(16 + (hi << 2) + r) << 14] = acc1[r] + red[( 4 + r) * 64 + lane];
            op[(size_t)(32 + (hi << 2) + r) << 14] = acc2[r] + red[( 8 + r) * 64 + lane];
            op[(size_t)(48 + (hi << 2) + r) << 14] = acc3[r] + red[(12 + r) * 64 + lane];
        }
    }
}

// -------------------------------------------------------------------------
extern "C" void kernel_launch(void* const* d_in, const int* in_sizes, int n_in,
                              void* d_out, int out_size, void* d_ws, size_t ws_size,
                              hipStream_t stream)
{
    const float* x        = (const float*)d_in[0];
    const float* offset_w = (const float*)d_in[1];
    const float* offset_b = (const float*)d_in[2];
    const float* mod_w    = (const float*)d_in[3];
    const float* mod_b    = (const float*)d_in[4];
    const float* weight   = (const float*)d_in[5];
    float* out = (float*)d_out;

    // Workspace (u16), total ~8.1 MiB:
    //   Wb : 36864 | OWb : 18432 | xt : 4 batches * HW * C = 4,194,304
    u16* Wb  = (u16*)d_ws;
    u16* OWb = Wb + 36864;
    u16* xt  = OWb + 18432;

    repack<<<216, 256, 0, stream>>>(weight, offset_w, mod_w, Wb, OWb);
    prep_t<<<1024, 256, 0, stream>>>(x, xt);
    fused_dcn<<<2048, 256, 0, stream>>>(xt, Wb, OWb, offset_b, mod_b, out);
}

// Round 10
// 79.372 us; speedup vs baseline: 1.0293x; 1.0293x over previous
//
#include <hip/hip_runtime.h>
#include <hip/hip_bf16.h>
#include <math.h>

typedef unsigned short u16;
typedef unsigned int   u32;
typedef __attribute__((ext_vector_type(8))) short short8;
typedef __attribute__((ext_vector_type(4))) float f32x4;

// Problem constants
#define B_  4
#define C_  64
#define H_  128
#define W_  128
#define O_  64
#define HW_ (H_ * W_)

__device__ __forceinline__ u16 f2bf(float f) {
    __hip_bfloat16 h = __float2bfloat16(f);
    u16 u; __builtin_memcpy(&u, &h, 2); return u;
}
__device__ __forceinline__ float bf2f(u16 u) {
    return __uint_as_float((u32)u << 16);
}
// pack two f32 -> [hi|lo] bf16 pair; plain C++ so the scheduler can move it
// (guide T12/m240: inline-asm cvt_pk is a scheduling black box, -37%)
__device__ __forceinline__ u32 pkbf(float lo, float hi) {
    return ((u32)f2bf(hi) << 16) | (u32)f2bf(lo);
}
__device__ __forceinline__ float bflo(u32 v) { return __uint_as_float(v << 16); }
__device__ __forceinline__ float bfhi(u32 v) { return __uint_as_float(v & 0xffff0000u); }

// -------------------------------------------------------------------------
// repack: Wb  (4 otile,18 ks,64 lane,8 j) bf16  from weight (O,C,3,3)
//         OWb (2 otile,18 ks,64 lane,8 j) bf16  from ow|mw|0
// K index convention: kidx = tap*64 + c  (tap-major, channel minor)
// A-frag (16x16x32): lane l holds A[o = l&15][k = ks*32 + (l>>4)*8 + j]
// -------------------------------------------------------------------------
__global__ __launch_bounds__(256) void repack(
    const float* __restrict__ weight,
    const float* __restrict__ ow, const float* __restrict__ mw,
    u16* __restrict__ Wb, u16* __restrict__ OWb)
{
    int t = blockIdx.x * 256 + threadIdx.x;      // 216 blocks = 55296 threads
    if (t < 36864) {                             // Wb
        int e = t;
        int j = e & 7, ln = (e >> 3) & 63;
        int ks = (e >> 9) % 18, ot = e / 9216;
        int o = ot * 16 + (ln & 15);
        int kidx = ks * 32 + ((ln >> 4) << 3) + j;
        int k = kidx >> 6, c = kidx & 63;
        Wb[e] = f2bf(weight[((size_t)(o * 64 + c)) * 9 + k]);
    } else {                                     // OWb
        int e = t - 36864;
        int j = e & 7, ln = (e >> 3) & 63;
        int ks = (e >> 9) % 18, ot = e / 9216;
        int o = ot * 16 + (ln & 15);
        int kidx = ks * 32 + ((ln >> 4) << 3) + j;
        int k = kidx >> 6, c = kidx & 63;
        float v = 0.0f;
        if (o < 18)      v = ow[((size_t)(o * 64 + c)) * 9 + k];
        else if (o < 27) v = mw[((size_t)((o - 18) * 64 + c)) * 9 + k];
        OWb[e] = f2bf(v);
    }
}

// -------------------------------------------------------------------------
// prep_t: transpose all 4 batches of x (B,C,H,W) f32 -> xt (B,H,W,C) bf16
// -------------------------------------------------------------------------
__global__ __launch_bounds__(256) void prep_t(
    const float* __restrict__ x, u16* __restrict__ xt)
{
    __shared__ float tile[64][65];
    int i = blockIdx.x, t = threadIdx.x;        // 1024 blocks
    int lb = i >> 8;                            // 0..3
    int pix0 = (i & 255) << 6;
    const float* xb = x + ((size_t)lb << 20);   // lb * C*HW
#pragma unroll
    for (int it = 0; it < 16; ++it) {
        int e = it * 256 + t;
        int c = e >> 6, pl = e & 63;
        tile[c][pl] = xb[((size_t)c << 14) + pix0 + pl];
    }
    __syncthreads();
    u16* xo = xt + ((((size_t)lb << 14) + pix0) << 6);
#pragma unroll
    for (int it = 0; it < 16; ++it) {
        int e = it * 256 + t;
        int c = e & 63, pl = e >> 6;
        xo[((size_t)pl << 6) + c] = f2bf(tile[c][pl]);
    }
}

// -------------------------------------------------------------------------
// fused_dcn: CHANNEL-SPLIT wave pairs (round-8 structure) + manual 2-deep
// software pipeline in K2. Block = 256 = 4 waves = 2 pixel groups x 2
// channel halves. Each pixel group (16 pixels, one row segment):
//   K1  : otile k2h of offset/mask conv (18 MFMAs), B-frags direct from
//         global xt -> param LDS
//   st1 : bilinear corner byte-offsets (int4) + bf16 weights -> LDS
//   K2  : 2-deep pipeline: prefetch tap t+1's params + 4 corner gathers
//         while interpolating tap t and feeding 4 o-tile MFMAs
//         (ks = tap*2+k2h, partial-K accumulate)
//   red : k2h=1 writes partial acc to LDS; k2h=0 adds and stores.
// -------------------------------------------------------------------------
__global__ __launch_bounds__(256, 6) void fused_dcn(
    const u16* __restrict__ xt,
    const u16* __restrict__ Wb, const u16* __restrict__ OWb,
    const float* __restrict__ ob, const float* __restrict__ mb,
    float* __restrict__ out)
{
    __shared__ float param[2][27][16];              //  3456 B
    __shared__ __align__(16) char scratch[2][5760]; // 11520 B: pwp|pww, later red

    const int t = threadIdx.x;
    const int lane = t & 63;
    const int wv = t >> 6;          // 0..3
    const int pg = wv >> 1;         // pixel group 0..1
    const int k2h = wv & 1;         // channel half / K1 o-tile
    const int mypix = lane & 15;
    const int hi = lane >> 4;       // channel octet within half

    int bid0 = blockIdx.x;          // 2048 blocks
    const int bid = (bid0 & 7) * 256 + (bid0 >> 3);   // XCD swizzle (bijective)
    const int task = (bid << 1) + pg;  // 0..4095 pixel-group task
    const int lb = task >> 10;      // batch
    const int pix0 = (task & 1023) << 4;
    const int h  = pix0 >> 7;       // 16 pixels share one row
    const int w0 = pix0 & 127;

    const u16* xtb = xt + ((size_t)lb << 20);
    int4*    pwp = (int4*)(scratch[pg]);            // 144 * 16 = 4608 B
    ushort4* pww = (ushort4*)(scratch[pg] + 4608);  // 144 *  8 = 1152 B

    // ---- K1: offset/mask conv, o-tile = k2h, direct global im2col ----
    f32x4 k1 = {0.f, 0.f, 0.f, 0.f};
#pragma unroll
    for (int ks = 0; ks < 18; ++ks) {
        const int tap = ks >> 1;
        const int ky = tap / 3, kx = tap % 3;
        int y  = h - 1 + ky;
        int xx = w0 + mypix - 1 + kx;
        bool valid = ((unsigned)y < (unsigned)H_) && ((unsigned)xx < (unsigned)W_);
        int idx = ((y & 127) << 7) + (xx & 127);    // wrapped -> safe address
        uint4 raw = *(const uint4*)(xtb + ((size_t)idx << 6) + ((ks & 1) << 5) + (hi << 3));
        raw.x = valid ? raw.x : 0u;
        raw.y = valid ? raw.y : 0u;
        raw.z = valid ? raw.z : 0u;
        raw.w = valid ? raw.w : 0u;
        short8 bfr;
        __builtin_memcpy(&bfr, &raw, 16);
        short8 wa = ((const short8*)OWb)[(k2h * 18 + ks) * 64 + lane];
        k1 = __builtin_amdgcn_mfma_f32_16x16x32_bf16(wa, bfr, k1, 0, 0, 0);
    }
#pragma unroll
    for (int r = 0; r < 4; ++r) {
        int oc = (k2h << 4) + (hi << 2) + r;
        if (oc < 18) {
            param[pg][oc][mypix] = k1[r] + ob[oc];
        } else if (oc < 27) {
            float s = k1[r] + mb[oc - 18];
            param[pg][oc][mypix] = 2.0f / (1.0f + __expf(-s));
        }
    }
    __syncthreads();

    // ---- step 1: bilinear corner offsets + weights (pair's 128 lanes) ----
    {
        int t128 = (k2h << 6) + lane;
#pragma unroll
        for (int it = 0; it < 2; ++it) {
            int p = (it << 7) + t128;
            if (p < 144) {
                int tap = p >> 4, pixl = p & 15;
                int ky = tap / 3, kx = tap % 3;
                float dy = param[pg][2 * tap][pixl];
                float dx = param[pg][2 * tap + 1][pixl];
                float m  = param[pg][18 + tap][pixl];
                float py = (float)(h - 1 + ky) + dy;
                float px = (float)(w0 + pixl - 1 + kx) + dx;
                float y0f = floorf(py), x0f = floorf(px);
                float fy = py - y0f, fx = px - x0f;
                int y0 = (int)y0f, x0 = (int)x0f;
                int y1 = y0 + 1, x1 = x0 + 1;
                bool vy0 = (unsigned)y0 < (unsigned)H_;
                bool vy1 = (unsigned)y1 < (unsigned)H_;
                bool vx0 = (unsigned)x0 < (unsigned)W_;
                bool vx1 = (unsigned)x1 < (unsigned)W_;
                float w00 = (1.f - fy) * (1.f - fx) * m; if (!(vy0 && vx0)) w00 = 0.f;
                float w01 = (1.f - fy) * fx          * m; if (!(vy0 && vx1)) w01 = 0.f;
                float w10 = fy * (1.f - fx)          * m; if (!(vy1 && vx0)) w10 = 0.f;
                float w11 = fy * fx                   * m; if (!(vy1 && vx1)) w11 = 0.f;
                int y0c = min(max(y0, 0), H_ - 1);
                int y1c = min(max(y1, 0), H_ - 1);
                int x0c = min(max(x0, 0), W_ - 1);
                int x1c = min(max(x1, 0), W_ - 1);
                // byte offsets into xt batch slab: pos (elem) * 64ch * 2B = pos<<7
                pwp[p] = make_int4(((y0c << 7) + x0c) << 7, ((y0c << 7) + x1c) << 7,
                                   ((y1c << 7) + x0c) << 7, ((y1c << 7) + x1c) << 7);
                pww[p] = make_ushort4(f2bf(w00), f2bf(w01), f2bf(w10), f2bf(w11));
            }
        }
    }
    __syncthreads();

    // ---- K2: 2-deep pipelined gather + in-register B-frag + 4 MFMAs/tap ----
    f32x4 acc0 = {0.f,0.f,0.f,0.f}, acc1 = {0.f,0.f,0.f,0.f};
    f32x4 acc2 = {0.f,0.f,0.f,0.f}, acc3 = {0.f,0.f,0.f,0.f};
    const char* xb8 = (const char*)xtb;
    const int co = (hi << 4) + (k2h << 6);     // byte offset of my channel octet

    // prologue: tap 0 params + corners
    int4    ofs = pwp[mypix];
    ushort4 wq  = pww[mypix];
    uint4 r00 = *(const uint4*)(xb8 + ofs.x + co);
    uint4 r01 = *(const uint4*)(xb8 + ofs.y + co);
    uint4 r10 = *(const uint4*)(xb8 + ofs.z + co);
    uint4 r11 = *(const uint4*)(xb8 + ofs.w + co);

#pragma unroll 1
    for (int tap = 0; tap < 9; ++tap) {
        // ---- prefetch tap+1 (issued before current interp consumes loads) ----
        int np = (tap < 8) ? ((tap + 1) << 4) + mypix : mypix;
        int4    nofs = pwp[np];
        ushort4 nwq  = pww[np];
        uint4 n00 = *(const uint4*)(xb8 + nofs.x + co);
        uint4 n01 = *(const uint4*)(xb8 + nofs.y + co);
        uint4 n10 = *(const uint4*)(xb8 + nofs.z + co);
        uint4 n11 = *(const uint4*)(xb8 + nofs.w + co);

        // ---- interpolate current tap ----
        float wtx = bf2f(wq.x), wty = bf2f(wq.y);
        float wtz = bf2f(wq.z), wtw = bf2f(wq.w);
        const u32* q00 = (const u32*)&r00;
        const u32* q01 = (const u32*)&r01;
        const u32* q10 = (const u32*)&r10;
        const u32* q11 = (const u32*)&r11;
        u32 bw[4];
#pragma unroll
        for (int q = 0; q < 4; ++q) {
            float slo = bflo(q00[q]) * wtx;
            slo = fmaf(bflo(q01[q]), wty, slo);
            slo = fmaf(bflo(q10[q]), wtz, slo);
            slo = fmaf(bflo(q11[q]), wtw, slo);
            float shi = bfhi(q00[q]) * wtx;
            shi = fmaf(bfhi(q01[q]), wty, shi);
            shi = fmaf(bfhi(q10[q]), wtz, shi);
            shi = fmaf(bfhi(q11[q]), wtw, shi);
            bw[q] = pkbf(slo, shi);
        }
        short8 bfr;
        __builtin_memcpy(&bfr, bw, 16);
        int ks = (tap << 1) + k2h;
        short8 a0 = ((const short8*)Wb)[(0 * 18 + ks) * 64 + lane];
        short8 a1 = ((const short8*)Wb)[(1 * 18 + ks) * 64 + lane];
        short8 a2 = ((const short8*)Wb)[(2 * 18 + ks) * 64 + lane];
        short8 a3 = ((const short8*)Wb)[(3 * 18 + ks) * 64 + lane];
        acc0 = __builtin_amdgcn_mfma_f32_16x16x32_bf16(a0, bfr, acc0, 0, 0, 0);
        acc1 = __builtin_amdgcn_mfma_f32_16x16x32_bf16(a1, bfr, acc1, 0, 0, 0);
        acc2 = __builtin_amdgcn_mfma_f32_16x16x32_bf16(a2, bfr, acc2, 0, 0, 0);
        acc3 = __builtin_amdgcn_mfma_f32_16x16x32_bf16(a3, bfr, acc3, 0, 0, 0);

        // ---- rotate pipeline ----
        ofs = nofs; wq = nwq;
        r00 = n00; r01 = n01; r10 = n10; r11 = n11;
    }
    __syncthreads();                    // all K2 reads of pwp/pww done

    // ---- reduce across the wave pair (red overlays dead pwp/pww) ----
    float* red = (float*)scratch[pg];   // 16 * 64 * 4 = 4096 B
    if (k2h) {
#pragma unroll
        for (int r = 0; r < 4; ++r) {
            red[( 0 + r) * 64 + lane] = acc0[r];
            red[( 4 + r) * 64 + lane] = acc1[r];
            red[( 8 + r) * 64 + lane] = acc2[r];
            red[(12 + r) * 64 + lane] = acc3[r];
        }
    }
    __syncthreads();
    if (!k2h) {
        float* op = out + ((size_t)lb << 20) + pix0 + mypix;
#pragma unroll
        for (int r = 0; r < 4; ++r) {
            op[(size_t)( 0 + (hi << 2) + r) << 14] = acc0[r] + red[( 0 + r) * 64 + lane];
            op[(size_t)(16 + (hi << 2) + r) << 14] = acc1[r] + red[( 4 + r) * 64 + lane];
            op[(size_t)(32 + (hi << 2) + r) << 14] = acc2[r] + red[( 8 + r) * 64 + lane];
            op[(size_t)(48 + (hi << 2) + r) << 14] = acc3[r] + red[(12 + r) * 64 + lane];
        }
    }
}

// -------------------------------------------------------------------------
extern "C" void kernel_launch(void* const* d_in, const int* in_sizes, int n_in,
                              void* d_out, int out_size, void* d_ws, size_t ws_size,
                              hipStream_t stream)
{
    const float* x        = (const float*)d_in[0];
    const float* offset_w = (const float*)d_in[1];
    const float* offset_b = (const float*)d_in[2];
    const float* mod_w    = (const float*)d_in[3];
    const float* mod_b    = (const float*)d_in[4];
    const float* weight   = (const float*)d_in[5];
    float* out = (float*)d_out;

    // Workspace (u16), total ~8.1 MiB:
    //   Wb : 36864 | OWb : 18432 | xt : 4 batches * HW * C = 4,194,304
    u16* Wb  = (u16*)d_ws;
    u16* OWb = Wb + 36864;
    u16* xt  = OWb + 18432;

    repack<<<216, 256, 0, stream>>>(weight, offset_w, mod_w, Wb, OWb);
    prep_t<<<1024, 256, 0, stream>>>(x, xt);
    fused_dcn<<<2048, 256, 0, stream>>>(xt, Wb, OWb, offset_b, mod_b, out);
}

// Round 11
// 73.706 us; speedup vs baseline: 1.1085x; 1.0769x over previous
//
#include <hip/hip_runtime.h>
#include <hip/hip_bf16.h>
#include <math.h>

typedef unsigned short u16;
typedef unsigned int   u32;
typedef __attribute__((ext_vector_type(8))) short short8;
typedef __attribute__((ext_vector_type(4))) float f32x4;

// Problem constants
#define B_  4
#define C_  64
#define H_  128
#define W_  128
#define O_  64
#define HW_ (H_ * W_)

__device__ __forceinline__ u16 f2bf(float f) {
    __hip_bfloat16 h = __float2bfloat16(f);
    u16 u; __builtin_memcpy(&u, &h, 2); return u;
}
__device__ __forceinline__ float bf2f(u16 u) {
    return __uint_as_float((u32)u << 16);
}
// pack two f32 -> [hi|lo] bf16 pair; plain C++ so the scheduler can move it
__device__ __forceinline__ u32 pkbf(float lo, float hi) {
    return ((u32)f2bf(hi) << 16) | (u32)f2bf(lo);
}
__device__ __forceinline__ float bflo(u32 v) { return __uint_as_float(v << 16); }
__device__ __forceinline__ float bfhi(u32 v) { return __uint_as_float(v & 0xffff0000u); }

// -------------------------------------------------------------------------
// prep: blocks 0..1023   : transpose x (B,C,H,W) f32 -> xt (B,H,W,C) bf16
//       blocks 1024..1239: repack weight->Wb, ow|mw->OWb (A-frag order)
// K index convention: kidx = tap*64 + c  (tap-major, channel minor)
// A-frag (16x16x32): lane l holds A[o = l&15][k = ks*32 + (l>>4)*8 + j]
// -------------------------------------------------------------------------
__global__ __launch_bounds__(256) void prep(
    const float* __restrict__ x, const float* __restrict__ weight,
    const float* __restrict__ ow, const float* __restrict__ mw,
    u16* __restrict__ xt, u16* __restrict__ Wb, u16* __restrict__ OWb)
{
    int i = blockIdx.x, t = threadIdx.x;
    if (i < 1024) {                             // transpose
        __shared__ float tile[64][65];
        int lb = i >> 8;                        // 0..3
        int pix0 = (i & 255) << 6;
        const float* xb = x + ((size_t)lb << 20);
#pragma unroll
        for (int it = 0; it < 16; ++it) {
            int e = it * 256 + t;
            int c = e >> 6, pl = e & 63;
            tile[c][pl] = xb[((size_t)c << 14) + pix0 + pl];
        }
        __syncthreads();
        u16* xo = xt + ((((size_t)lb << 14) + pix0) << 6);
#pragma unroll
        for (int it = 0; it < 16; ++it) {
            int e = it * 256 + t;
            int c = e & 63, pl = e >> 6;
            xo[((size_t)pl << 6) + c] = f2bf(tile[c][pl]);
        }
    } else {
        int e = (i - 1024) * 256 + t;           // 0..55295
        if (e < 36864) {                        // Wb
            int j = e & 7, ln = (e >> 3) & 63;
            int ks = (e >> 9) % 18, ot = e / 9216;
            int o = ot * 16 + (ln & 15);
            int kidx = ks * 32 + ((ln >> 4) << 3) + j;
            int k = kidx >> 6, c = kidx & 63;
            Wb[e] = f2bf(weight[((size_t)(o * 64 + c)) * 9 + k]);
        } else {                                // OWb
            int e2 = e - 36864;
            int j = e2 & 7, ln = (e2 >> 3) & 63;
            int ks = (e2 >> 9) % 18, ot = e2 / 9216;
            int o = ot * 16 + (ln & 15);
            int kidx = ks * 32 + ((ln >> 4) << 3) + j;
            int k = kidx >> 6, c = kidx & 63;
            float v = 0.0f;
            if (o < 18)      v = ow[((size_t)(o * 64 + c)) * 9 + k];
            else if (o < 27) v = mw[((size_t)((o - 18) * 64 + c)) * 9 + k];
            OWb[e2] = f2bf(v);
        }
    }
}

// -------------------------------------------------------------------------
// fused_dcn: CHANNEL-SPLIT wave pairs + PINNED 2-deep software pipeline.
// Block = 256 = 4 waves = 2 pixel groups x 2 channel halves.
//   K1  : otile k2h of offset/mask conv; loads issued in 2 batches of 9
//         (static array) so 9 im2col loads are in flight, then MFMAs.
//   st1 : bilinear corner byte-offsets (int4) + bf16 weights -> LDS
//   K2  : fully unrolled taps; per tap [prefetch tap+1: params + 4 corner
//         gathers + 4 A-frags] -> sched_barrier(0) -> [interp tap, 4 MFMA].
//         The fence stops the scheduler sinking the prefetch, so 8 loads
//         stay outstanding across each interp+MFMA block.
//   red : k2h=1 writes partial acc to LDS; k2h=0 adds and stores.
// launch_bounds(256,4): VGPR cap 128 (target ~110 live, no spill).
// -------------------------------------------------------------------------
__global__ __launch_bounds__(256, 4) void fused_dcn(
    const u16* __restrict__ xt,
    const u16* __restrict__ Wb, const u16* __restrict__ OWb,
    const float* __restrict__ ob, const float* __restrict__ mb,
    float* __restrict__ out)
{
    __shared__ float param[2][27][16];              //  3456 B
    __shared__ __align__(16) char scratch[2][5760]; // 11520 B: pwp|pww, later red

    const int t = threadIdx.x;
    const int lane = t & 63;
    const int wv = t >> 6;          // 0..3
    const int pg = wv >> 1;         // pixel group 0..1
    const int k2h = wv & 1;         // channel half / K1 o-tile
    const int mypix = lane & 15;
    const int hi = lane >> 4;       // channel octet within half

    int bid0 = blockIdx.x;          // 2048 blocks
    const int bid = (bid0 & 7) * 256 + (bid0 >> 3);   // XCD swizzle (bijective)
    const int task = (bid << 1) + pg;  // 0..4095 pixel-group task
    const int lb = task >> 10;      // batch
    const int pix0 = (task & 1023) << 4;
    const int h  = pix0 >> 7;       // 16 pixels share one row
    const int w0 = pix0 & 127;

    const u16* xtb = xt + ((size_t)lb << 20);
    int4*    pwp = (int4*)(scratch[pg]);            // 144 * 16 = 4608 B
    ushort4* pww = (ushort4*)(scratch[pg] + 4608);  // 144 *  8 = 1152 B

    // ---- K1: offset/mask conv, o-tile = k2h; 2 batches of 9 in-flight loads ----
    f32x4 k1 = {0.f, 0.f, 0.f, 0.f};
#pragma unroll
    for (int half = 0; half < 2; ++half) {
        uint4 raw[9];
#pragma unroll
        for (int q = 0; q < 9; ++q) {
            int ks = half * 9 + q;
            int tap = ks >> 1;
            int ky = tap / 3, kx = tap % 3;
            int y  = h - 1 + ky;
            int xx = w0 + mypix - 1 + kx;
            int idx = ((y & 127) << 7) + (xx & 127);    // wrapped -> safe
            raw[q] = *(const uint4*)(xtb + ((size_t)idx << 6) + ((ks & 1) << 5) + (hi << 3));
        }
        __builtin_amdgcn_sched_barrier(0);
#pragma unroll
        for (int q = 0; q < 9; ++q) {
            int ks = half * 9 + q;
            int tap = ks >> 1;
            int ky = tap / 3, kx = tap % 3;
            int y  = h - 1 + ky;
            int xx = w0 + mypix - 1 + kx;
            bool valid = ((unsigned)y < (unsigned)H_) && ((unsigned)xx < (unsigned)W_);
            uint4 rw = raw[q];
            rw.x = valid ? rw.x : 0u;
            rw.y = valid ? rw.y : 0u;
            rw.z = valid ? rw.z : 0u;
            rw.w = valid ? rw.w : 0u;
            short8 bfr;
            __builtin_memcpy(&bfr, &rw, 16);
            short8 wa = ((const short8*)OWb)[(k2h * 18 + ks) * 64 + lane];
            k1 = __builtin_amdgcn_mfma_f32_16x16x32_bf16(wa, bfr, k1, 0, 0, 0);
        }
    }
#pragma unroll
    for (int r = 0; r < 4; ++r) {
        int oc = (k2h << 4) + (hi << 2) + r;
        if (oc < 18) {
            param[pg][oc][mypix] = k1[r] + ob[oc];
        } else if (oc < 27) {
            float s = k1[r] + mb[oc - 18];
            param[pg][oc][mypix] = 2.0f / (1.0f + __expf(-s));
        }
    }
    __syncthreads();

    // ---- step 1: bilinear corner offsets + weights (pair's 128 lanes) ----
    {
        int t128 = (k2h << 6) + lane;
#pragma unroll
        for (int it = 0; it < 2; ++it) {
            int p = (it << 7) + t128;
            if (p < 144) {
                int tap = p >> 4, pixl = p & 15;
                int ky = tap / 3, kx = tap % 3;
                float dy = param[pg][2 * tap][pixl];
                float dx = param[pg][2 * tap + 1][pixl];
                float m  = param[pg][18 + tap][pixl];
                float py = (float)(h - 1 + ky) + dy;
                float px = (float)(w0 + pixl - 1 + kx) + dx;
                float y0f = floorf(py), x0f = floorf(px);
                float fy = py - y0f, fx = px - x0f;
                int y0 = (int)y0f, x0 = (int)x0f;
                int y1 = y0 + 1, x1 = x0 + 1;
                bool vy0 = (unsigned)y0 < (unsigned)H_;
                bool vy1 = (unsigned)y1 < (unsigned)H_;
                bool vx0 = (unsigned)x0 < (unsigned)W_;
                bool vx1 = (unsigned)x1 < (unsigned)W_;
                float w00 = (1.f - fy) * (1.f - fx) * m; if (!(vy0 && vx0)) w00 = 0.f;
                float w01 = (1.f - fy) * fx          * m; if (!(vy0 && vx1)) w01 = 0.f;
                float w10 = fy * (1.f - fx)          * m; if (!(vy1 && vx0)) w10 = 0.f;
                float w11 = fy * fx                   * m; if (!(vy1 && vx1)) w11 = 0.f;
                int y0c = min(max(y0, 0), H_ - 1);
                int y1c = min(max(y1, 0), H_ - 1);
                int x0c = min(max(x0, 0), W_ - 1);
                int x1c = min(max(x1, 0), W_ - 1);
                // byte offsets into xt batch slab: pos (elem) * 64ch * 2B = pos<<7
                pwp[p] = make_int4(((y0c << 7) + x0c) << 7, ((y0c << 7) + x1c) << 7,
                                   ((y1c << 7) + x0c) << 7, ((y1c << 7) + x1c) << 7);
                pww[p] = make_ushort4(f2bf(w00), f2bf(w01), f2bf(w10), f2bf(w11));
            }
        }
    }
    __syncthreads();

    // ---- K2: pinned 2-deep pipeline, fully unrolled taps ----
    f32x4 acc0 = {0.f,0.f,0.f,0.f}, acc1 = {0.f,0.f,0.f,0.f};
    f32x4 acc2 = {0.f,0.f,0.f,0.f}, acc3 = {0.f,0.f,0.f,0.f};
    const char* xb8 = (const char*)xtb;
    const int co = (hi << 4) + (k2h << 6);     // byte offset of my channel octet

    // prologue: tap 0 params + corners + A-frags
    int4    ofs = pwp[mypix];
    ushort4 wq  = pww[mypix];
    uint4 c00 = *(const uint4*)(xb8 + ofs.x + co);
    uint4 c01 = *(const uint4*)(xb8 + ofs.y + co);
    uint4 c10 = *(const uint4*)(xb8 + ofs.z + co);
    uint4 c11 = *(const uint4*)(xb8 + ofs.w + co);
    short8 a0 = ((const short8*)Wb)[(0 * 18 + k2h) * 64 + lane];
    short8 a1 = ((const short8*)Wb)[(1 * 18 + k2h) * 64 + lane];
    short8 a2 = ((const short8*)Wb)[(2 * 18 + k2h) * 64 + lane];
    short8 a3 = ((const short8*)Wb)[(3 * 18 + k2h) * 64 + lane];

#pragma unroll
    for (int tap = 0; tap < 9; ++tap) {
        // ---- prefetch tap+1 (pinned above the fence; stays in flight) ----
        int4 nofs; ushort4 nwq;
        uint4 n00, n01, n10, n11;
        short8 b0, b1, b2, b3;
        if (tap < 8) {
            nofs = pwp[((tap + 1) << 4) + mypix];
            nwq  = pww[((tap + 1) << 4) + mypix];
            n00 = *(const uint4*)(xb8 + nofs.x + co);
            n01 = *(const uint4*)(xb8 + nofs.y + co);
            n10 = *(const uint4*)(xb8 + nofs.z + co);
            n11 = *(const uint4*)(xb8 + nofs.w + co);
            int nks = ((tap + 1) << 1) + k2h;
            b0 = ((const short8*)Wb)[(0 * 18 + nks) * 64 + lane];
            b1 = ((const short8*)Wb)[(1 * 18 + nks) * 64 + lane];
            b2 = ((const short8*)Wb)[(2 * 18 + nks) * 64 + lane];
            b3 = ((const short8*)Wb)[(3 * 18 + nks) * 64 + lane];
        }
        __builtin_amdgcn_sched_barrier(0);

        // ---- interpolate current tap ----
        float wtx = bf2f(wq.x), wty = bf2f(wq.y);
        float wtz = bf2f(wq.z), wtw = bf2f(wq.w);
        const u32* q00 = (const u32*)&c00;
        const u32* q01 = (const u32*)&c01;
        const u32* q10 = (const u32*)&c10;
        const u32* q11 = (const u32*)&c11;
        u32 bw[4];
#pragma unroll
        for (int q = 0; q < 4; ++q) {
            float slo = bflo(q00[q]) * wtx;
            slo = fmaf(bflo(q01[q]), wty, slo);
            slo = fmaf(bflo(q10[q]), wtz, slo);
            slo = fmaf(bflo(q11[q]), wtw, slo);
            float shi = bfhi(q00[q]) * wtx;
            shi = fmaf(bfhi(q01[q]), wty, shi);
            shi = fmaf(bfhi(q10[q]), wtz, shi);
            shi = fmaf(bfhi(q11[q]), wtw, shi);
            bw[q] = pkbf(slo, shi);
        }
        short8 bfr;
        __builtin_memcpy(&bfr, bw, 16);
        acc0 = __builtin_amdgcn_mfma_f32_16x16x32_bf16(a0, bfr, acc0, 0, 0, 0);
        acc1 = __builtin_amdgcn_mfma_f32_16x16x32_bf16(a1, bfr, acc1, 0, 0, 0);
        acc2 = __builtin_amdgcn_mfma_f32_16x16x32_bf16(a2, bfr, acc2, 0, 0, 0);
        acc3 = __builtin_amdgcn_mfma_f32_16x16x32_bf16(a3, bfr, acc3, 0, 0, 0);

        // ---- rotate pipeline (static: loop fully unrolled) ----
        if (tap < 8) {
            ofs = nofs; wq = nwq;
            c00 = n00; c01 = n01; c10 = n10; c11 = n11;
            a0 = b0; a1 = b1; a2 = b2; a3 = b3;
        }
    }
    __syncthreads();                    // all K2 reads of pwp/pww done

    // ---- reduce across the wave pair (red overlays dead pwp/pww) ----
    float* red = (float*)scratch[pg];   // 16 * 64 * 4 = 4096 B
    if (k2h) {
#pragma unroll
        for (int r = 0; r < 4; ++r) {
            red[( 0 + r) * 64 + lane] = acc0[r];
            red[( 4 + r) * 64 + lane] = acc1[r];
            red[( 8 + r) * 64 + lane] = acc2[r];
            red[(12 + r) * 64 + lane] = acc3[r];
        }
    }
    __syncthreads();
    if (!k2h) {
        float* op = out + ((size_t)lb << 20) + pix0 + mypix;
#pragma unroll
        for (int r = 0; r < 4; ++r) {
            op[(size_t)( 0 + (hi << 2) + r) << 14] = acc0[r] + red[( 0 + r) * 64 + lane];
            op[(size_t)(16 + (hi << 2) + r) << 14] = acc1[r] + red[( 4 + r) * 64 + lane];
            op[(size_t)(32 + (hi << 2) + r) << 14] = acc2[r] + red[( 8 + r) * 64 + lane];
            op[(size_t)(48 + (hi << 2) + r) << 14] = acc3[r] + red[(12 + r) * 64 + lane];
        }
    }
}

// -------------------------------------------------------------------------
extern "C" void kernel_launch(void* const* d_in, const int* in_sizes, int n_in,
                              void* d_out, int out_size, void* d_ws, size_t ws_size,
                              hipStream_t stream)
{
    const float* x        = (const float*)d_in[0];
    const float* offset_w = (const float*)d_in[1];
    const float* offset_b = (const float*)d_in[2];
    const float* mod_w    = (const float*)d_in[3];
    const float* mod_b    = (const float*)d_in[4];
    const float* weight   = (const float*)d_in[5];
    float* out = (float*)d_out;

    // Workspace (u16), total ~8.1 MiB:
    //   Wb : 36864 | OWb : 18432 | xt : 4 batches * HW * C = 4,194,304
    u16* Wb  = (u16*)d_ws;
    u16* OWb = Wb + 36864;
    u16* xt  = OWb + 18432;

    prep<<<1240, 256, 0, stream>>>(x, weight, offset_w, mod_w, xt, Wb, OWb);
    fused_dcn<<<2048, 256, 0, stream>>>(xt, Wb, OWb, offset_b, mod_b, out);
}